// Round 6
// baseline (314.602 us; speedup 1.0000x reference)
//
#include <hip/hip_runtime.h>
#include <stdint.h>

#define NPTS 4096
#define NW   64            // 64-bit words per adjacency row
#define SENT NPTS
#define MAXSP 512
#define ROWS 8             // rows per wave in k_adj

// ---------------- K0: pack coords into float4(x,y,z,sq) ---------------------
__global__ void k_prep(const float* __restrict__ coords,
                       float4* __restrict__ pts){
#pragma clang fp contract(off)
  int g = blockIdx.x * blockDim.x + threadIdx.x;   // 8*4096
  float x = coords[g*3+0], y = coords[g*3+1], z = coords[g*3+2];
  // sq: round each square, then sequential adds (XLA mul + reduce, no FMA)
  float sq = ((x*x) + (y*y)) + (z*z);
  pts[g] = make_float4(x, y, z, sq);
}

// ---------------- K1: adjacency bitset + degree/core ------------------------
// one wave handles ROWS=8 rows; word k built with __ballot (j = k*64+lane)
__global__ void k_adj(const float4* __restrict__ pts,
                      unsigned long long* __restrict__ adj,
                      int* __restrict__ core){
#pragma clang fp contract(off)
  int wv   = (blockIdx.x * blockDim.x + threadIdx.x) >> 6;   // 4096 waves
  int lane = threadIdx.x & 63;
  int b  = wv >> 9;                 // 512 waves per batch
  int i0 = (wv & 511) << 3;         // first of 8 rows
  const float4* pb = pts + (b << 12);
  float4 pi[ROWS];
  #pragma unroll
  for (int r = 0; r < ROWS; ++r) pi[r] = pb[i0 + r];
  const float EPS2 = (float)(0.06 * 0.06);
  unsigned long long w[ROWS];
  int deg[ROWS];
  #pragma unroll
  for (int r = 0; r < ROWS; ++r){ w[r] = 0ULL; deg[r] = 0; }
  #pragma unroll 2
  for (int k = 0; k < 64; ++k){
    float4 pj = pb[(k << 6) + lane];
    #pragma unroll
    for (int r = 0; r < ROWS; ++r){
      // dot: ascending-k FMA chain, first product plainly rounded (XLA gebp)
      float dot = __builtin_fmaf(pi[r].z, pj.z,
                  __builtin_fmaf(pi[r].y, pj.y, pi[r].x * pj.x));
      // rn(s - rn(2*dot)) == fma(-2,dot,s) since 2*dot is exact
      float d2 = __builtin_fmaf(-2.0f, dot, pi[r].w + pj.w);
      unsigned long long bal = __ballot(d2 <= EPS2);
      if (lane == k) w[r] = bal;
      deg[r] += __popcll(bal);
    }
  }
  size_t rowg = ((size_t)b << 12) + i0;
  #pragma unroll
  for (int r = 0; r < ROWS; ++r) adj[(rowg + r) * NW + lane] = w[r];
  if (lane == 0){
    #pragma unroll
    for (int r = 0; r < ROWS; ++r) core[rowg + r] = (deg[r] >= 3) ? 1 : 0;
  }
}

// ---------------- K2: core bitset (one wave per batch) ----------------------
__global__ void k_corebits(const int* __restrict__ core,
                           unsigned long long* __restrict__ corebits){
  int b = blockIdx.x;
  int lane = threadIdx.x;   // 64 threads
  unsigned long long myword = 0ULL;
  for (int k = 0; k < 64; ++k){
    unsigned long long bal = __ballot(core[(b << 12) + (k << 6) + lane] != 0);
    if (lane == k) myword = bal;
  }
  corebits[(b << 6) + lane] = myword;
}

// ---------------- LDS union-find (union-by-min: root = component min) -------
__device__ __forceinline__ int find_lds(int* p, int x){
  while (true){
    int px = p[x];
    if (px == x) return x;
    int ppx = p[px];
    if (ppx == px) return px;
    p[x] = ppx;            // path halving: writes always point to an ancestor
    x = ppx;
  }
}

__device__ __forceinline__ void union_lds(int* p, int a, int b){
  a = find_lds(p, a);
  b = find_lds(p, b);
  while (a != b){
    int lo = min(a, b), hi = max(a, b);
    int old = atomicCAS(&p[hi], hi, lo);   // LDS CAS
    if (old == hi || old == lo) return;
    a = lo; b = old;                        // old = hi's true parent (< hi)
  }
}

// ---------------- K3: per-batch CC — single-pass union-find in LDS ----------
// One block per batch. 16 waves scan adjacency rows (lane = word, coalesced);
// core-core j>i edges union directly into the 16 KB LDS parent array.
// Unique fixed point: every component's root is its min index (order-free).
__global__ __launch_bounds__(1024) void k_cc(const unsigned long long* __restrict__ adj,
                                             const unsigned long long* __restrict__ corebits,
                                             const int* __restrict__ core,
                                             int* __restrict__ lab_g){
  __shared__ int lab[NPTS];
  int b = blockIdx.x, t = threadIdx.x;
  for (int s = 0; s < 4; ++s){ int v = (t << 2) + s; lab[v] = v; }
  __syncthreads();
  int wv = t >> 6, lane = t & 63;          // 16 waves
  unsigned long long cb = corebits[(b << 6) + lane];
  int base = lane << 6;
  const int* cg = core + (b << 12);
  for (int i = wv; i < NPTS; i += 16){
    if (!cg[i]) continue;                  // wave-uniform branch
    unsigned long long m = adj[(((size_t)(b << 12)) + i) * NW + lane] & cb;
    if (base + 63 <= i) m = 0ULL;                       // whole word j <= i
    else if (base <= i) m &= (~0ULL) << (i - base + 1); // keep j > i
    while (m){
      int bit = __builtin_ctzll(m);
      m &= m - 1;
      union_lds(lab, i, base + bit);
    }
  }
  __syncthreads();
  // all unions done; concurrent halving finds are benign
  for (int s = 0; s < 4; ++s){
    int v = (t << 2) + s;
    lab_g[(b << 12) + v] = find_lds(lab, v);
  }
}

// ---------------- K4: labels (core: lab[i]; border: min core-neighbor lab) --
__global__ void k_labels(const unsigned long long* __restrict__ adj,
                         const unsigned long long* __restrict__ corebits,
                         const int* __restrict__ core,
                         const int* __restrict__ lab_g,
                         int* __restrict__ labels){
  int wv   = (blockIdx.x * blockDim.x + threadIdx.x) >> 6;
  int lane = threadIdx.x & 63;
  int b = wv >> 12;
  int i = wv & (NPTS - 1);
  const int* lb = lab_g + (b << 12);
  unsigned long long m = adj[(size_t)wv * NW + lane] & corebits[(b << 6) + lane];
  int mn = SENT;
  int base = lane << 6;
  while (m){
    int bit = __builtin_ctzll(m);
    m &= m - 1;
    mn = min(mn, lb[base + bit]);
  }
  #pragma unroll
  for (int off = 32; off; off >>= 1) mn = min(mn, __shfl_xor(mn, off));
  if (lane == 0){
    labels[wv] = core[wv] ? lb[i] : mn;   // SENT if no core neighbor
  }
}

// ---------------- K5: per-batch finalize (noise fill, compact, cap) ---------
__global__ __launch_bounds__(1024) void k_final(const int* __restrict__ labels_g,
                                                int* __restrict__ out){
  __shared__ int LAB[NPTS];
  __shared__ int A[NPTS];
  __shared__ int B[NPTS];
  __shared__ int scanbuf[1024];
  __shared__ int sMost;
  int b = blockIdx.x;
  int t = threadIdx.x;
  const int* lg = labels_g + (b << 12);

  for (int s = 0; s < 4; ++s){ int v = (t << 2) + s; LAB[v] = lg[v]; A[v] = 0; }
  if (t == 0) sMost = -1;
  __syncthreads();
  for (int s = 0; s < 4; ++s){ int l = LAB[(t << 2) + s]; if (l < SENT) atomicAdd(&A[l], 1); }
  __syncthreads();
  for (int s = 0; s < 4; ++s){
    int v = (t << 2) + s; int c = A[v];
    if (c > 0) atomicMax(&sMost, (c << 13) | (4095 - v));
  }
  __syncthreads();
  int most = (sMost >= 0) ? (4095 - (sMost & 8191)) : 0;
  for (int s = 0; s < 4; ++s){ int v = (t << 2) + s; if (LAB[v] == SENT) LAB[v] = most; B[v] = 0; }
  __syncthreads();
  for (int s = 0; s < 4; ++s) B[LAB[(t << 2) + s]] = 1;
  __syncthreads();
  int pv[4]; int ls = 0;
  for (int s = 0; s < 4; ++s){ pv[s] = B[(t << 2) + s]; ls += pv[s]; }
  scanbuf[t] = ls;
  __syncthreads();
  for (int off = 1; off < 1024; off <<= 1){
    int x = scanbuf[t];
    int y = (t >= off) ? scanbuf[t - off] : 0;
    __syncthreads();
    scanbuf[t] = x + y;
    __syncthreads();
  }
  int ncl = scanbuf[1023];
  int run = (t > 0) ? scanbuf[t - 1] : 0;
  for (int s = 0; s < 4; ++s){ run += pv[s]; B[(t << 2) + s] = run - 1; }
  __syncthreads();
  for (int s = 0; s < 4; ++s){ int v = (t << 2) + s; LAB[v] = B[LAB[v]]; }
  __syncthreads();
  if (ncl > MAXSP){
    for (int s = 0; s < 4; ++s) A[(t << 2) + s] = 0;
    __syncthreads();
    for (int s = 0; s < 4; ++s) atomicAdd(&A[LAB[(t << 2) + s]], 1);
    __syncthreads();
    for (int s = 0; s < 4; ++s){
      int v = (t << 2) + s;
      int keyv = A[v] * NPTS + v;
      int pos = 0;
      for (int u = 0; u < NPTS; ++u) pos += ((A[u] * NPTS + u) < keyv) ? 1 : 0;
      B[v] = (pos >= NPTS - MAXSP) ? (pos - (NPTS - MAXSP)) : 0;
    }
    __syncthreads();
    for (int s = 0; s < 4; ++s){ int v = (t << 2) + s; LAB[v] = B[LAB[v]]; }
    __syncthreads();
  }
  int* og = out + (b << 12);
  for (int s = 0; s < 4; ++s){ int v = (t << 2) + s; og[v] = LAB[v]; }
}

// ---------------- launch ----------------------------------------------------
extern "C" void kernel_launch(void* const* d_in, const int* in_sizes, int n_in,
                              void* d_out, int out_size, void* d_ws, size_t ws_size,
                              hipStream_t stream){
  const float* coords = (const float*)d_in[0];
  int* out = (int*)d_out;
  int batches = in_sizes[0] / (NPTS * 3);   // 8

  char* ws = (char*)d_ws;
  unsigned long long* adj = (unsigned long long*)ws;                  // 16 MB
  size_t off = (size_t)batches * NPTS * NW * sizeof(unsigned long long);
  int* core   = (int*)(ws + off); off += (size_t)batches * NPTS * sizeof(int);
  unsigned long long* corebits = (unsigned long long*)(ws + off);
  off += (size_t)batches * 64 * sizeof(unsigned long long);
  int* lab_g  = (int*)(ws + off); off += (size_t)batches * NPTS * sizeof(int);
  int* labels = (int*)(ws + off); off += (size_t)batches * NPTS * sizeof(int);
  float4* pts = (float4*)(ws + off); off += (size_t)batches * NPTS * sizeof(float4);

  int npts_all = batches * NPTS;
  // K0: pack float4(x,y,z,sq)
  k_prep<<<npts_all / 256, 256, 0, stream>>>(coords, pts);
  // K1: adjacency, 8 rows per wave
  k_adj<<<npts_all / (ROWS * 4), 256, 0, stream>>>(pts, adj, core);
  // K2: core bitset
  k_corebits<<<batches, 64, 0, stream>>>(core, corebits);
  // K3: per-batch single-pass union-find in LDS
  k_cc<<<batches, 1024, 0, stream>>>(adj, corebits, core, lab_g);
  // K4: label extraction
  k_labels<<<npts_all / 4, 256, 0, stream>>>(adj, corebits, core, lab_g, labels);
  // K5: per-batch finalize
  k_final<<<batches, 1024, 0, stream>>>(labels, out);
}

// Round 7
// 150.827 us; speedup vs baseline: 2.0859x; 2.0859x over previous
//
#include <hip/hip_runtime.h>
#include <stdint.h>

#define NPTS 4096
#define NW   64            // 64-bit words per adjacency row
#define SENT NPTS
#define MAXSP 512
#define ROWS 8             // rows per wave in k_adj

// ---------------- global union-find helpers (R3-proven) ---------------------
__device__ __forceinline__ int uf_find(int* p, int x){
  while (true){
    int px = p[x];
    if (px == x) return x;
    int ppx = p[px];
    if (ppx == px) return px;
    p[x] = ppx;            // path halving (benign race; links only decrease)
    x = ppx;
  }
}

__device__ __forceinline__ int uf_find_ro(const int* __restrict__ p, int x){
  int px;
  while ((px = p[x]) != x) x = px;
  return x;
}

// CAS-return-driven hook loop: progress guaranteed by atomic return values
// (max(a,b) strictly decreases on every failed CAS).
__device__ __forceinline__ void uf_union(int* p, int a, int b){
  a = uf_find(p, a);
  b = uf_find(p, b);
  while (a != b){
    int lo = min(a, b), hi = max(a, b);
    int old = atomicCAS(&p[hi], hi, lo);
    if (old == hi || old == lo) return;
    a = lo; b = old;
  }
}

// ---------------- K0: pack coords into float4(x,y,z,sq) ---------------------
__global__ void k_prep(const float* __restrict__ coords,
                       float4* __restrict__ pts){
#pragma clang fp contract(off)
  int g = blockIdx.x * blockDim.x + threadIdx.x;   // 8*4096
  float x = coords[g*3+0], y = coords[g*3+1], z = coords[g*3+2];
  // sq: round each square, then sequential adds (XLA mul + reduce, no FMA)
  float sq = ((x*x) + (y*y)) + (z*z);
  pts[g] = make_float4(x, y, z, sq);
}

// ---------------- K1: adjacency bitset + degree/core ------------------------
// one wave handles ROWS=8 rows; word k built with __ballot (j = k*64+lane)
__global__ void k_adj(const float4* __restrict__ pts,
                      unsigned long long* __restrict__ adj,
                      int* __restrict__ core){
#pragma clang fp contract(off)
  int wv   = (blockIdx.x * blockDim.x + threadIdx.x) >> 6;   // 4096 waves
  int lane = threadIdx.x & 63;
  int b  = wv >> 9;                 // 512 waves per batch
  int i0 = (wv & 511) << 3;         // first of 8 rows
  const float4* pb = pts + (b << 12);
  float4 pi[ROWS];
  #pragma unroll
  for (int r = 0; r < ROWS; ++r) pi[r] = pb[i0 + r];
  const float EPS2 = (float)(0.06 * 0.06);
  unsigned long long w[ROWS];
  int deg[ROWS];
  #pragma unroll
  for (int r = 0; r < ROWS; ++r){ w[r] = 0ULL; deg[r] = 0; }
  #pragma unroll 2
  for (int k = 0; k < 64; ++k){
    float4 pj = pb[(k << 6) + lane];
    #pragma unroll
    for (int r = 0; r < ROWS; ++r){
      // dot: ascending-k FMA chain, first product plainly rounded (XLA gebp)
      float dot = __builtin_fmaf(pi[r].z, pj.z,
                  __builtin_fmaf(pi[r].y, pj.y, pi[r].x * pj.x));
      // rn(s - rn(2*dot)) == fma(-2,dot,s) since 2*dot is exact
      float d2 = __builtin_fmaf(-2.0f, dot, pi[r].w + pj.w);
      unsigned long long bal = __ballot(d2 <= EPS2);
      if (lane == k) w[r] = bal;
      deg[r] += __popcll(bal);
    }
  }
  size_t rowg = ((size_t)b << 12) + i0;
  #pragma unroll
  for (int r = 0; r < ROWS; ++r) adj[(rowg + r) * NW + lane] = w[r];
  if (lane == 0){
    #pragma unroll
    for (int r = 0; r < ROWS; ++r) core[rowg + r] = (deg[r] >= 3) ? 1 : 0;
  }
}

// ---------------- K2: core bitset (one wave per batch) ----------------------
__global__ void k_corebits(const int* __restrict__ core,
                           unsigned long long* __restrict__ corebits){
  int b = blockIdx.x;
  int lane = threadIdx.x;   // 64 threads
  unsigned long long myword = 0ULL;
  for (int k = 0; k < 64; ++k){
    unsigned long long bal = __ballot(core[(b << 12) + (k << 6) + lane] != 0);
    if (lane == k) myword = bal;
  }
  corebits[(b << 6) + lane] = myword;
}

// ---------------- K3: min-neighbor hook (no atomics, full-grid) -------------
// parent[i] = min core neighbor (incl. self) for core i — store to own slot.
__global__ void k_hook(const unsigned long long* __restrict__ adj,
                       const unsigned long long* __restrict__ corebits,
                       const int* __restrict__ core,
                       int* __restrict__ parent){
  int wv   = (blockIdx.x * blockDim.x + threadIdx.x) >> 6;   // global row
  int lane = threadIdx.x & 63;
  int b = wv >> 12;
  if (!core[wv]){ if (lane == 0) parent[wv] = wv & (NPTS - 1); return; }
  unsigned long long m = adj[(size_t)wv * NW + lane] & corebits[(b << 6) + lane];
  int mn = SENT;
  if (m) mn = (lane << 6) + __builtin_ctzll(m);
  #pragma unroll
  for (int off = 32; off; off >>= 1) mn = min(mn, __shfl_xor(mn, off));
  if (lane == 0) parent[wv] = mn;   // mn <= i (self bit is set for core i)
}

// ---------------- K4: per-batch LDS flatten of the hook forest --------------
// Pointer-jumping with barriers; monotone (values only move to ancestors),
// so intra-round races are safe. Residual depth handled by later finds.
__global__ __launch_bounds__(1024) void k_flat(int* __restrict__ parent){
  __shared__ int lab[NPTS];
  int b = blockIdx.x, t = threadIdx.x;
  int* pg = parent + (b << 12);
  for (int s = 0; s < 4; ++s){ int v = (t << 2) + s; lab[v] = pg[v]; }
  __syncthreads();
  for (int r = 0; r < 16; ++r){
    for (int s = 0; s < 4; ++s){
      int v = (t << 2) + s;
      int l = lab[v];
      int nl = lab[l];            // ancestor-of-ancestor is an ancestor
      if (nl < l) lab[v] = nl;
    }
    __syncthreads();
  }
  for (int s = 0; s < 4; ++s){ int v = (t << 2) + s; pg[v] = lab[v]; }
}

// ---------------- K5: union remaining inter-tree edges (j > i, full-grid) ---
__global__ void k_union2(const unsigned long long* __restrict__ adj,
                         const unsigned long long* __restrict__ corebits,
                         const int* __restrict__ core,
                         int* __restrict__ parent){
  int wv   = (blockIdx.x * blockDim.x + threadIdx.x) >> 6;
  int lane = threadIdx.x & 63;
  int b = wv >> 12;
  int i = wv & (NPTS - 1);
  if (!core[wv]) return;
  unsigned long long m = adj[(size_t)wv * NW + lane] & corebits[(b << 6) + lane];
  int base = lane << 6;
  if (base + 63 <= i) m = 0ULL;                       // whole word j <= i
  else if (base <= i) m &= (~0ULL) << (i - base + 1); // keep j > i
  int* p = parent + (b << 12);
  while (m){
    int bit = __builtin_ctzll(m);
    m &= m - 1;
    uf_union(p, i, base + bit);
  }
}

// ---------------- K6: labels (core: root; border: min core-neighbor root) ---
// parent is CONSTANT during this kernel (read-only finds).
__global__ void k_labels(const unsigned long long* __restrict__ adj,
                         const unsigned long long* __restrict__ corebits,
                         const int* __restrict__ core,
                         const int* __restrict__ parent,
                         int* __restrict__ labels){
  int wv   = (blockIdx.x * blockDim.x + threadIdx.x) >> 6;
  int lane = threadIdx.x & 63;
  int b = wv >> 12;
  int i = wv & (NPTS - 1);
  const int* p = parent + (b << 12);
  unsigned long long m = adj[(size_t)wv * NW + lane] & corebits[(b << 6) + lane];
  int mn = SENT;
  int base = lane << 6;
  while (m){
    int bit = __builtin_ctzll(m);
    m &= m - 1;
    mn = min(mn, uf_find_ro(p, base + bit));
  }
  #pragma unroll
  for (int off = 32; off; off >>= 1) mn = min(mn, __shfl_xor(mn, off));
  if (lane == 0){
    labels[wv] = core[wv] ? uf_find_ro(p, i) : mn;   // SENT if no core nbr
  }
}

// ---------------- K7: per-batch finalize (noise fill, compact, cap) ---------
__global__ __launch_bounds__(1024) void k_final(const int* __restrict__ labels_g,
                                                int* __restrict__ out){
  __shared__ int LAB[NPTS];
  __shared__ int A[NPTS];
  __shared__ int B[NPTS];
  __shared__ int scanbuf[1024];
  __shared__ int sMost;
  int b = blockIdx.x;
  int t = threadIdx.x;
  const int* lg = labels_g + (b << 12);

  for (int s = 0; s < 4; ++s){ int v = (t << 2) + s; LAB[v] = lg[v]; A[v] = 0; }
  if (t == 0) sMost = -1;
  __syncthreads();
  for (int s = 0; s < 4; ++s){ int l = LAB[(t << 2) + s]; if (l < SENT) atomicAdd(&A[l], 1); }
  __syncthreads();
  for (int s = 0; s < 4; ++s){
    int v = (t << 2) + s; int c = A[v];
    if (c > 0) atomicMax(&sMost, (c << 13) | (4095 - v));
  }
  __syncthreads();
  int most = (sMost >= 0) ? (4095 - (sMost & 8191)) : 0;
  for (int s = 0; s < 4; ++s){ int v = (t << 2) + s; if (LAB[v] == SENT) LAB[v] = most; B[v] = 0; }
  __syncthreads();
  for (int s = 0; s < 4; ++s) B[LAB[(t << 2) + s]] = 1;
  __syncthreads();
  int pv[4]; int ls = 0;
  for (int s = 0; s < 4; ++s){ pv[s] = B[(t << 2) + s]; ls += pv[s]; }
  scanbuf[t] = ls;
  __syncthreads();
  for (int off = 1; off < 1024; off <<= 1){
    int x = scanbuf[t];
    int y = (t >= off) ? scanbuf[t - off] : 0;
    __syncthreads();
    scanbuf[t] = x + y;
    __syncthreads();
  }
  int ncl = scanbuf[1023];
  int run = (t > 0) ? scanbuf[t - 1] : 0;
  for (int s = 0; s < 4; ++s){ run += pv[s]; B[(t << 2) + s] = run - 1; }
  __syncthreads();
  for (int s = 0; s < 4; ++s){ int v = (t << 2) + s; LAB[v] = B[LAB[v]]; }
  __syncthreads();
  if (ncl > MAXSP){
    for (int s = 0; s < 4; ++s) A[(t << 2) + s] = 0;
    __syncthreads();
    for (int s = 0; s < 4; ++s) atomicAdd(&A[LAB[(t << 2) + s]], 1);
    __syncthreads();
    for (int s = 0; s < 4; ++s){
      int v = (t << 2) + s;
      int keyv = A[v] * NPTS + v;
      int pos = 0;
      for (int u = 0; u < NPTS; ++u) pos += ((A[u] * NPTS + u) < keyv) ? 1 : 0;
      B[v] = (pos >= NPTS - MAXSP) ? (pos - (NPTS - MAXSP)) : 0;
    }
    __syncthreads();
    for (int s = 0; s < 4; ++s){ int v = (t << 2) + s; LAB[v] = B[LAB[v]]; }
    __syncthreads();
  }
  int* og = out + (b << 12);
  for (int s = 0; s < 4; ++s){ int v = (t << 2) + s; og[v] = LAB[v]; }
}

// ---------------- launch ----------------------------------------------------
extern "C" void kernel_launch(void* const* d_in, const int* in_sizes, int n_in,
                              void* d_out, int out_size, void* d_ws, size_t ws_size,
                              hipStream_t stream){
  const float* coords = (const float*)d_in[0];
  int* out = (int*)d_out;
  int batches = in_sizes[0] / (NPTS * 3);   // 8

  char* ws = (char*)d_ws;
  unsigned long long* adj = (unsigned long long*)ws;                  // 16 MB
  size_t off = (size_t)batches * NPTS * NW * sizeof(unsigned long long);
  int* core   = (int*)(ws + off); off += (size_t)batches * NPTS * sizeof(int);
  unsigned long long* corebits = (unsigned long long*)(ws + off);
  off += (size_t)batches * 64 * sizeof(unsigned long long);
  int* parent = (int*)(ws + off); off += (size_t)batches * NPTS * sizeof(int);
  int* labels = (int*)(ws + off); off += (size_t)batches * NPTS * sizeof(int);
  float4* pts = (float4*)(ws + off); off += (size_t)batches * NPTS * sizeof(float4);

  int npts_all = batches * NPTS;
  // K0: pack float4(x,y,z,sq)
  k_prep<<<npts_all / 256, 256, 0, stream>>>(coords, pts);
  // K1: adjacency, 8 rows per wave
  k_adj<<<npts_all / (ROWS * 4), 256, 0, stream>>>(pts, adj, core);
  // K2: core bitset
  k_corebits<<<batches, 64, 0, stream>>>(core, corebits);
  // K3: min-neighbor hook (atomic-free, full-grid)
  k_hook<<<npts_all / 4, 256, 0, stream>>>(adj, corebits, core, parent);
  // K4: per-batch LDS flatten of hook forest
  k_flat<<<batches, 1024, 0, stream>>>(parent);
  // K5: union inter-tree edges (finds are now ~1-2 hops)
  k_union2<<<npts_all / 4, 256, 0, stream>>>(adj, corebits, core, parent);
  // K6: label extraction
  k_labels<<<npts_all / 4, 256, 0, stream>>>(adj, corebits, core, parent, labels);
  // K7: per-batch finalize
  k_final<<<batches, 1024, 0, stream>>>(labels, out);
}

// Round 8
// 98.242 us; speedup vs baseline: 3.2023x; 1.5353x over previous
//
#include <hip/hip_runtime.h>
#include <stdint.h>

#define NPTS 4096
#define NW   64            // 64-bit words per adjacency row
#define SENT NPTS
#define MAXSP 512
#define ROWS 8             // rows per wave in k_adj
#define ECAP 65536         // edge capacity per batch (pairs; ~8x margin)

// ---------------- LDS union-find (union-by-min: root = component min) -------
// ECL-CC-style: parent values only decrease and always point to an ancestor;
// CAS only targets root slots; path-halving writes are benign. Block-local
// (LDS) -> no cross-XCD coherence concerns; __syncthreads orders phases.
__device__ __forceinline__ int find_lds(int* p, int x){
  while (true){
    int px = p[x];
    if (px == x) return x;
    int ppx = p[px];
    if (ppx == px) return px;
    p[x] = ppx;            // path halving
    x = ppx;
  }
}

__device__ __forceinline__ void union_lds(int* p, int a, int b){
  a = find_lds(p, a);
  b = find_lds(p, b);
  while (a != b){
    int lo = min(a, b), hi = max(a, b);
    int old = atomicCAS(&p[hi], hi, lo);   // LDS CAS
    if (old == hi || old == lo) return;
    a = lo; b = old;                        // old = hi's true parent (< hi)
  }
}

// ---------------- K0: pack coords into float4(x,y,z,sq) ---------------------
__global__ void k_prep(const float* __restrict__ coords,
                       float4* __restrict__ pts){
#pragma clang fp contract(off)
  int g = blockIdx.x * blockDim.x + threadIdx.x;   // 8*4096
  float x = coords[g*3+0], y = coords[g*3+1], z = coords[g*3+2];
  // sq: round each square, then sequential adds (XLA mul + reduce, no FMA)
  float sq = ((x*x) + (y*y)) + (z*z);
  pts[g] = make_float4(x, y, z, sq);
}

// ---------------- K1: adjacency + core + per-row j>i pair count -------------
// one wave handles ROWS=8 rows; word k built with __ballot (j = k*64+lane).
// After the loop, lane l holds word l of each row -> j>i count by wave-reduce.
__global__ void k_adj(const float4* __restrict__ pts,
                      unsigned long long* __restrict__ adj,
                      int* __restrict__ core,
                      int* __restrict__ rcnt){
#pragma clang fp contract(off)
  int wv   = (blockIdx.x * blockDim.x + threadIdx.x) >> 6;   // 4096 waves
  int lane = threadIdx.x & 63;
  int b  = wv >> 9;                 // 512 waves per batch
  int i0 = (wv & 511) << 3;         // first of 8 rows
  const float4* pb = pts + (b << 12);
  float4 pi[ROWS];
  #pragma unroll
  for (int r = 0; r < ROWS; ++r) pi[r] = pb[i0 + r];
  const float EPS2 = (float)(0.06 * 0.06);
  unsigned long long w[ROWS];
  int deg[ROWS];
  #pragma unroll
  for (int r = 0; r < ROWS; ++r){ w[r] = 0ULL; deg[r] = 0; }
  #pragma unroll 2
  for (int k = 0; k < 64; ++k){
    float4 pj = pb[(k << 6) + lane];
    #pragma unroll
    for (int r = 0; r < ROWS; ++r){
      // dot: ascending-k FMA chain, first product plainly rounded (XLA gebp)
      float dot = __builtin_fmaf(pi[r].z, pj.z,
                  __builtin_fmaf(pi[r].y, pj.y, pi[r].x * pj.x));
      // rn(s - rn(2*dot)) == fma(-2,dot,s) since 2*dot is exact
      float d2 = __builtin_fmaf(-2.0f, dot, pi[r].w + pj.w);
      unsigned long long bal = __ballot(d2 <= EPS2);
      if (lane == k) w[r] = bal;
      deg[r] += __popcll(bal);
    }
  }
  size_t rowg = ((size_t)b << 12) + i0;
  int base = lane << 6;
  #pragma unroll
  for (int r = 0; r < ROWS; ++r){
    adj[(rowg + r) * NW + lane] = w[r];
    // j>i count for row i0+r (lane l holds word l)
    int i = i0 + r;
    unsigned long long mm = w[r];
    if (base + 63 <= i) mm = 0ULL;
    else if (base <= i) mm &= (~0ULL) << (i - base + 1);
    int c = __popcll(mm);
    #pragma unroll
    for (int off = 32; off; off >>= 1) c += __shfl_xor(c, off);
    if (lane == 0) rcnt[rowg + r] = c;
  }
  if (lane == 0){
    #pragma unroll
    for (int r = 0; r < ROWS; ++r) core[rowg + r] = (deg[r] >= 3) ? 1 : 0;
  }
}

// ---------------- K2: core bitset (one wave per batch) ----------------------
__global__ void k_corebits(const int* __restrict__ core,
                           unsigned long long* __restrict__ corebits){
  int b = blockIdx.x;
  int lane = threadIdx.x;   // 64 threads
  unsigned long long myword = 0ULL;
  for (int k = 0; k < 64; ++k){
    unsigned long long bal = __ballot(core[(b << 12) + (k << 6) + lane] != 0);
    if (lane == k) myword = bal;
  }
  corebits[(b << 6) + lane] = myword;
}

// ---------------- K3: per-batch exclusive scan of row counts ----------------
__global__ __launch_bounds__(1024) void k_escan(const int* __restrict__ rcnt,
                                                int* __restrict__ roff,
                                                int* __restrict__ ecnt){
  __shared__ int sb[1024];
  int b = blockIdx.x, t = threadIdx.x;
  int v4[4]; int ls = 0;
  for (int s = 0; s < 4; ++s){ v4[s] = rcnt[(b << 12) + (t << 2) + s]; ls += v4[s]; }
  sb[t] = ls;
  __syncthreads();
  for (int off = 1; off < 1024; off <<= 1){
    int x = sb[t];
    int y = (t >= off) ? sb[t - off] : 0;
    __syncthreads();
    sb[t] = x + y;
    __syncthreads();
  }
  int run = (t > 0) ? sb[t - 1] : 0;
  for (int s = 0; s < 4; ++s){ roff[(b << 12) + (t << 2) + s] = run; run += v4[s]; }
  if (t == 1023) ecnt[b] = sb[1023];
}

// ---------------- K4: fill ALL j>i adjacent pairs at deterministic offsets --
__global__ void k_efill(const unsigned long long* __restrict__ adj,
                        const int* __restrict__ roff,
                        uint32_t* __restrict__ edges){
  int wv   = (blockIdx.x * blockDim.x + threadIdx.x) >> 6;
  int lane = threadIdx.x & 63;
  int b = wv >> 12;
  int i = wv & (NPTS - 1);
  unsigned long long m = adj[(size_t)wv * NW + lane];
  int base = lane << 6;
  if (base + 63 <= i) m = 0ULL;                       // whole word j <= i
  else if (base <= i) m &= (~0ULL) << (i - base + 1); // keep j > i
  int cnt = __popcll(m);
  int incl = cnt;                              // wave inclusive scan
  #pragma unroll
  for (int off = 1; off < 64; off <<= 1){
    int y = __shfl_up(incl, off);
    if (lane >= off) incl += y;
  }
  int pos = roff[wv] + incl - cnt;
  uint32_t* eb = edges + (size_t)b * ECAP;
  while (m){
    int bit = __builtin_ctzll(m);
    m &= m - 1;
    if (pos < ECAP) eb[pos] = ((uint32_t)i << 12) | (uint32_t)(base + bit);
    pos++;
  }
}

// ---------------- K5: per-batch CC — single-pass union-find in LDS ----------
// Edges stream ONCE from global (coalesced, independent); parent in LDS.
// Unique fixed point: every component's root is its min index (order-free).
__global__ __launch_bounds__(1024) void k_cc(const uint32_t* __restrict__ edges,
                                             const int* __restrict__ ecnt,
                                             const unsigned long long* __restrict__ corebits,
                                             int* __restrict__ lab_g){
  __shared__ int par[NPTS];
  __shared__ unsigned long long cb[64];
  int b = blockIdx.x, t = threadIdx.x;
  for (int s = 0; s < 4; ++s){ int v = (t << 2) + s; par[v] = v; }
  if (t < 64) cb[t] = corebits[(b << 6) + t];
  __syncthreads();
  int cnt = min(ecnt[b], ECAP);
  const uint32_t* eb = edges + (size_t)b * ECAP;
  for (int e = t; e < cnt; e += 1024){
    uint32_t pk = eb[e];
    int i = pk >> 12, j = pk & 4095;
    bool ci = (cb[i >> 6] >> (i & 63)) & 1ULL;
    bool cj = (cb[j >> 6] >> (j & 63)) & 1ULL;
    if (ci && cj) union_lds(par, i, j);
  }
  __syncthreads();
  // all unions complete; concurrent halving finds are benign
  for (int s = 0; s < 4; ++s){
    int v = (t << 2) + s;
    lab_g[(b << 12) + v] = find_lds(par, v);
  }
}

// ---------------- K6: labels (core: lab[i]; border: min core-neighbor lab) --
__global__ void k_labels(const unsigned long long* __restrict__ adj,
                         const unsigned long long* __restrict__ corebits,
                         const int* __restrict__ core,
                         const int* __restrict__ lab_g,
                         int* __restrict__ labels){
  int wv   = (blockIdx.x * blockDim.x + threadIdx.x) >> 6;
  int lane = threadIdx.x & 63;
  int b = wv >> 12;
  int i = wv & (NPTS - 1);
  const int* lb = lab_g + (b << 12);
  unsigned long long m = adj[(size_t)wv * NW + lane] & corebits[(b << 6) + lane];
  int mn = SENT;
  int base = lane << 6;
  while (m){
    int bit = __builtin_ctzll(m);
    m &= m - 1;
    mn = min(mn, lb[base + bit]);
  }
  #pragma unroll
  for (int off = 32; off; off >>= 1) mn = min(mn, __shfl_xor(mn, off));
  if (lane == 0){
    labels[wv] = core[wv] ? lb[i] : mn;   // SENT if no core neighbor
  }
}

// ---------------- K7: per-batch finalize (noise fill, compact, cap) ---------
__global__ __launch_bounds__(1024) void k_final(const int* __restrict__ labels_g,
                                                int* __restrict__ out){
  __shared__ int LAB[NPTS];
  __shared__ int A[NPTS];
  __shared__ int B[NPTS];
  __shared__ int scanbuf[1024];
  __shared__ int sMost;
  int b = blockIdx.x;
  int t = threadIdx.x;
  const int* lg = labels_g + (b << 12);

  for (int s = 0; s < 4; ++s){ int v = (t << 2) + s; LAB[v] = lg[v]; A[v] = 0; }
  if (t == 0) sMost = -1;
  __syncthreads();
  for (int s = 0; s < 4; ++s){ int l = LAB[(t << 2) + s]; if (l < SENT) atomicAdd(&A[l], 1); }
  __syncthreads();
  for (int s = 0; s < 4; ++s){
    int v = (t << 2) + s; int c = A[v];
    if (c > 0) atomicMax(&sMost, (c << 13) | (4095 - v));
  }
  __syncthreads();
  int most = (sMost >= 0) ? (4095 - (sMost & 8191)) : 0;
  for (int s = 0; s < 4; ++s){ int v = (t << 2) + s; if (LAB[v] == SENT) LAB[v] = most; B[v] = 0; }
  __syncthreads();
  for (int s = 0; s < 4; ++s) B[LAB[(t << 2) + s]] = 1;
  __syncthreads();
  int pv[4]; int ls = 0;
  for (int s = 0; s < 4; ++s){ pv[s] = B[(t << 2) + s]; ls += pv[s]; }
  scanbuf[t] = ls;
  __syncthreads();
  for (int off = 1; off < 1024; off <<= 1){
    int x = scanbuf[t];
    int y = (t >= off) ? scanbuf[t - off] : 0;
    __syncthreads();
    scanbuf[t] = x + y;
    __syncthreads();
  }
  int ncl = scanbuf[1023];
  int run = (t > 0) ? scanbuf[t - 1] : 0;
  for (int s = 0; s < 4; ++s){ run += pv[s]; B[(t << 2) + s] = run - 1; }
  __syncthreads();
  for (int s = 0; s < 4; ++s){ int v = (t << 2) + s; LAB[v] = B[LAB[v]]; }
  __syncthreads();
  if (ncl > MAXSP){
    for (int s = 0; s < 4; ++s) A[(t << 2) + s] = 0;
    __syncthreads();
    for (int s = 0; s < 4; ++s) atomicAdd(&A[LAB[(t << 2) + s]], 1);
    __syncthreads();
    for (int s = 0; s < 4; ++s){
      int v = (t << 2) + s;
      int keyv = A[v] * NPTS + v;
      int pos = 0;
      for (int u = 0; u < NPTS; ++u) pos += ((A[u] * NPTS + u) < keyv) ? 1 : 0;
      B[v] = (pos >= NPTS - MAXSP) ? (pos - (NPTS - MAXSP)) : 0;
    }
    __syncthreads();
    for (int s = 0; s < 4; ++s){ int v = (t << 2) + s; LAB[v] = B[LAB[v]]; }
    __syncthreads();
  }
  int* og = out + (b << 12);
  for (int s = 0; s < 4; ++s){ int v = (t << 2) + s; og[v] = LAB[v]; }
}

// ---------------- launch ----------------------------------------------------
extern "C" void kernel_launch(void* const* d_in, const int* in_sizes, int n_in,
                              void* d_out, int out_size, void* d_ws, size_t ws_size,
                              hipStream_t stream){
  const float* coords = (const float*)d_in[0];
  int* out = (int*)d_out;
  int batches = in_sizes[0] / (NPTS * 3);   // 8

  char* ws = (char*)d_ws;
  unsigned long long* adj = (unsigned long long*)ws;                  // 16 MB
  size_t off = (size_t)batches * NPTS * NW * sizeof(unsigned long long);
  int* core   = (int*)(ws + off); off += (size_t)batches * NPTS * sizeof(int);
  unsigned long long* corebits = (unsigned long long*)(ws + off);
  off += (size_t)batches * 64 * sizeof(unsigned long long);
  int* lab_g  = (int*)(ws + off); off += (size_t)batches * NPTS * sizeof(int);
  int* labels = (int*)(ws + off); off += (size_t)batches * NPTS * sizeof(int);
  float4* pts = (float4*)(ws + off); off += (size_t)batches * NPTS * sizeof(float4);
  int* rcnt   = (int*)(ws + off); off += (size_t)batches * NPTS * sizeof(int);
  int* roff   = (int*)(ws + off); off += (size_t)batches * NPTS * sizeof(int);
  int* ecnt   = (int*)(ws + off); off += 256;
  uint32_t* edges = (uint32_t*)(ws + off); off += (size_t)batches * ECAP * sizeof(uint32_t);

  int npts_all = batches * NPTS;
  // K0: pack float4(x,y,z,sq)
  k_prep<<<npts_all / 256, 256, 0, stream>>>(coords, pts);
  // K1: adjacency + core + per-row j>i counts (fused)
  k_adj<<<npts_all / (ROWS * 4), 256, 0, stream>>>(pts, adj, core, rcnt);
  // K2: core bitset
  k_corebits<<<batches, 64, 0, stream>>>(core, corebits);
  // K3: per-batch scan -> deterministic edge offsets
  k_escan<<<batches, 1024, 0, stream>>>(rcnt, roff, ecnt);
  // K4: fill all j>i adjacent pairs
  k_efill<<<npts_all / 4, 256, 0, stream>>>(adj, roff, edges);
  // K5: per-batch single-pass union-find in LDS (edges streamed once)
  k_cc<<<batches, 1024, 0, stream>>>(edges, ecnt, corebits, lab_g);
  // K6: label extraction (direct gathers, no finds)
  k_labels<<<npts_all / 4, 256, 0, stream>>>(adj, corebits, core, lab_g, labels);
  // K7: per-batch finalize
  k_final<<<batches, 1024, 0, stream>>>(labels, out);
}

// Round 9
// 85.486 us; speedup vs baseline: 3.6802x; 1.1492x over previous
//
#include <hip/hip_runtime.h>
#include <stdint.h>

#define NPTS 4096
#define NW   64            // 64-bit words per adjacency row
#define SENT NPTS
#define MAXSP 512
#define ROWS 4             // rows per wave in k_adj
#define ECAP 65536         // edge capacity per batch (pairs)
#define ECACHE 16384       // edges cached in LDS by k_mega (64 KB)

// ---------------- LDS union-find (union-by-min: root = component min) -------
__device__ __forceinline__ int find_lds(int* p, int x){
  while (true){
    int px = p[x];
    if (px == x) return x;
    int ppx = p[px];
    if (ppx == px) return px;
    p[x] = ppx;            // path halving (benign race; links only decrease)
    x = ppx;
  }
}

__device__ __forceinline__ void union_lds(int* p, int a, int b){
  a = find_lds(p, a);
  b = find_lds(p, b);
  while (a != b){
    int lo = min(a, b), hi = max(a, b);
    int old = atomicCAS(&p[hi], hi, lo);   // LDS CAS
    if (old == hi || old == lo) return;
    a = lo; b = old;                        // old = hi's true parent (< hi)
  }
}

// ---------------- K0: pack coords into float4(x,y,z,sq) ---------------------
__global__ void k_prep(const float* __restrict__ coords,
                       float4* __restrict__ pts){
#pragma clang fp contract(off)
  int g = blockIdx.x * blockDim.x + threadIdx.x;   // 8*4096
  float x = coords[g*3+0], y = coords[g*3+1], z = coords[g*3+2];
  // sq: round each square, then sequential adds (XLA mul + reduce, no FMA)
  float sq = ((x*x) + (y*y)) + (z*z);
  pts[g] = make_float4(x, y, z, sq);
}

// ---------------- K1: UPPER-TRIANGLE adjacency + per-row j>i count ----------
// d2(i,j) is bit-exactly symmetric (IEEE mul/add commute; identical fma
// chain), so only j>i is computed. k-loop starts at the diagonal word.
// One wave = ROWS=4 rows; word k built with __ballot (j = k*64+lane).
__global__ void k_adj(const float4* __restrict__ pts,
                      unsigned long long* __restrict__ adj,
                      int* __restrict__ rcnt){
#pragma clang fp contract(off)
  int wv   = (blockIdx.x * blockDim.x + threadIdx.x) >> 6;   // 8192 waves
  int lane = threadIdx.x & 63;
  int b  = wv >> 10;                // 1024 waves per batch
  int i0 = (wv & 1023) << 2;        // first of 4 rows
  const float4* pb = pts + (b << 12);
  float4 pi[ROWS];
  #pragma unroll
  for (int r = 0; r < ROWS; ++r) pi[r] = pb[i0 + r];
  const float EPS2 = (float)(0.06 * 0.06);
  int W = i0 >> 6;                  // diagonal word (same for all 4 rows)
  unsigned long long w[ROWS];
  #pragma unroll
  for (int r = 0; r < ROWS; ++r) w[r] = 0ULL;
  #pragma unroll 2
  for (int k = W; k < 64; ++k){
    float4 pj = pb[(k << 6) + lane];
    #pragma unroll
    for (int r = 0; r < ROWS; ++r){
      // dot: ascending-k FMA chain, first product plainly rounded (XLA gebp)
      float dot = __builtin_fmaf(pi[r].z, pj.z,
                  __builtin_fmaf(pi[r].y, pj.y, pi[r].x * pj.x));
      // rn(s - rn(2*dot)) == fma(-2,dot,s) since 2*dot is exact
      float d2 = __builtin_fmaf(-2.0f, dot, pi[r].w + pj.w);
      unsigned long long bal = __ballot(d2 <= EPS2);
      if (lane == k) w[r] = bal;
    }
  }
  size_t rowg = ((size_t)b << 12) + i0;
  int base = lane << 6;
  #pragma unroll
  for (int r = 0; r < ROWS; ++r){
    int i = i0 + r;
    unsigned long long mm = w[r];
    if (base + 63 <= i) mm = 0ULL;                       // whole word j <= i
    else if (base <= i) mm &= (~0ULL) << (i - base + 1); // keep j > i
    int c = __popcll(mm);
    #pragma unroll
    for (int off = 32; off; off >>= 1) c += __shfl_xor(c, off);
    if (lane == 0) rcnt[rowg + r] = c;
    if (lane >= W) adj[(rowg + r) * NW + lane] = mm;     // sub-diag left stale
  }
}

// ---------------- K2: per-batch exclusive scan of row counts ----------------
__global__ __launch_bounds__(1024) void k_escan(const int* __restrict__ rcnt,
                                                int* __restrict__ roff,
                                                int* __restrict__ ecnt){
  __shared__ int sb[1024];
  int b = blockIdx.x, t = threadIdx.x;
  int v4[4]; int ls = 0;
  for (int s = 0; s < 4; ++s){ v4[s] = rcnt[(b << 12) + (t << 2) + s]; ls += v4[s]; }
  sb[t] = ls;
  __syncthreads();
  for (int off = 1; off < 1024; off <<= 1){
    int x = sb[t];
    int y = (t >= off) ? sb[t - off] : 0;
    __syncthreads();
    sb[t] = x + y;
    __syncthreads();
  }
  int run = (t > 0) ? sb[t - 1] : 0;
  for (int s = 0; s < 4; ++s){ roff[(b << 12) + (t << 2) + s] = run; run += v4[s]; }
  if (t == 1023) ecnt[b] = sb[1023];
}

// ---------------- K3: fill all j>i adjacent pairs at deterministic offsets --
__global__ void k_efill(const unsigned long long* __restrict__ adj,
                        const int* __restrict__ roff,
                        uint32_t* __restrict__ edges){
  int wv   = (blockIdx.x * blockDim.x + threadIdx.x) >> 6;
  int lane = threadIdx.x & 63;
  int b = wv >> 12;
  int i = wv & (NPTS - 1);
  int base = lane << 6;
  unsigned long long m = 0ULL;
  if (base + 63 > i){                          // skip stale sub-diag words
    m = adj[(size_t)wv * NW + lane];           // pre-masked by k_adj
  }
  int cnt = __popcll(m);
  int incl = cnt;                              // wave inclusive scan
  #pragma unroll
  for (int off = 1; off < 64; off <<= 1){
    int y = __shfl_up(incl, off);
    if (lane >= off) incl += y;
  }
  int pos = roff[wv] + incl - cnt;
  uint32_t* eb = edges + (size_t)b * ECAP;
  while (m){
    int bit = __builtin_ctzll(m);
    m &= m - 1;
    if (pos < ECAP) eb[pos] = ((uint32_t)i << 12) | (uint32_t)(base + bit);
    pos++;
  }
}

// ---------------- K4: per-batch mega kernel --------------------------------
// incidence -> core -> union-find -> labels -> border relax -> finalize,
// all in LDS; edges stream once from global, cached in LDS for reuse.
// deg[i] = 1 + incidence[i] (self always adjacent: d2(i,i) ~ 1ulp << eps^2),
// so core <=> incidence >= 2 (MIN_SAMPLES=3).
__global__ __launch_bounds__(1024) void k_mega(const uint32_t* __restrict__ edges,
                                               const int* __restrict__ ecnt,
                                               int* __restrict__ out){
  __shared__ int par[NPTS];          // phase 1: incidence; then UF parent
  __shared__ int LAB[NPTS];
  __shared__ unsigned char corea[NPTS];
  __shared__ uint32_t ec[ECACHE];    // finalize aliases A/B/scan over this
  __shared__ int sMost;
  int b = blockIdx.x, t = threadIdx.x;
  int cnt = min(ecnt[b], ECAP);
  const uint32_t* eb = edges + (size_t)b * ECAP;
  for (int s = 0; s < 4; ++s){ int v = (t << 2) + s; par[v] = 0; }
  if (t == 0) sMost = -1;
  __syncthreads();
  // P1: incidence counts + LDS edge cache
  for (int e = t; e < cnt; e += 1024){
    uint32_t pk = eb[e];
    if (e < ECACHE) ec[e] = pk;
    atomicAdd(&par[pk >> 12], 1);
    atomicAdd(&par[pk & 4095], 1);
  }
  __syncthreads();
  // P2: core flags, then reinit par as UF identity
  for (int s = 0; s < 4; ++s){ int v = (t << 2) + s; corea[v] = (par[v] >= 2) ? 1 : 0; }
  __syncthreads();
  for (int s = 0; s < 4; ++s){ int v = (t << 2) + s; par[v] = v; }
  __syncthreads();
  // P3: union core-core edges (single pass; fixed point = component min)
  for (int e = t; e < cnt; e += 1024){
    uint32_t pk = (e < ECACHE) ? ec[e] : eb[e];
    int u = pk >> 12, v = pk & 4095;
    if (corea[u] && corea[v]) union_lds(par, u, v);
  }
  __syncthreads();
  // P4: base labels (core: root; else SENT)
  for (int s = 0; s < 4; ++s){
    int v = (t << 2) + s;
    LAB[v] = corea[v] ? find_lds(par, v) : SENT;
  }
  __syncthreads();
  // P5: border relax — min core-neighbor root via the same edge list
  for (int e = t; e < cnt; e += 1024){
    uint32_t pk = (e < ECACHE) ? ec[e] : eb[e];
    int u = pk >> 12, v = pk & 4095;
    int cu = corea[u], cv = corea[v];
    if (cu && !cv)      atomicMin(&LAB[v], find_lds(par, u));
    else if (cv && !cu) atomicMin(&LAB[u], find_lds(par, v));
  }
  __syncthreads();
  // P6: finalize (noise fill, compact, cap) — A/B/scan aliased over ec
  int* A     = (int*)ec;
  int* Bb    = A + NPTS;
  int* scanb = Bb + NPTS;
  for (int s = 0; s < 4; ++s){ int v = (t << 2) + s; A[v] = 0; }
  __syncthreads();
  for (int s = 0; s < 4; ++s){ int l = LAB[(t << 2) + s]; if (l < SENT) atomicAdd(&A[l], 1); }
  __syncthreads();
  for (int s = 0; s < 4; ++s){
    int v = (t << 2) + s; int c = A[v];
    if (c > 0) atomicMax(&sMost, (c << 13) | (4095 - v));   // tie -> smallest label
  }
  __syncthreads();
  int most = (sMost >= 0) ? (4095 - (sMost & 8191)) : 0;
  for (int s = 0; s < 4; ++s){ int v = (t << 2) + s; if (LAB[v] == SENT) LAB[v] = most; Bb[v] = 0; }
  __syncthreads();
  for (int s = 0; s < 4; ++s) Bb[LAB[(t << 2) + s]] = 1;
  __syncthreads();
  int pv[4]; int ls = 0;
  for (int s = 0; s < 4; ++s){ pv[s] = Bb[(t << 2) + s]; ls += pv[s]; }
  scanb[t] = ls;
  __syncthreads();
  for (int off = 1; off < 1024; off <<= 1){
    int x = scanb[t];
    int y = (t >= off) ? scanb[t - off] : 0;
    __syncthreads();
    scanb[t] = x + y;
    __syncthreads();
  }
  int ncl = scanb[1023];
  int run = (t > 0) ? scanb[t - 1] : 0;
  for (int s = 0; s < 4; ++s){ run += pv[s]; Bb[(t << 2) + s] = run - 1; }
  __syncthreads();
  for (int s = 0; s < 4; ++s){ int v = (t << 2) + s; LAB[v] = Bb[LAB[v]]; }
  __syncthreads();
  if (ncl > MAXSP){
    for (int s = 0; s < 4; ++s) A[(t << 2) + s] = 0;
    __syncthreads();
    for (int s = 0; s < 4; ++s) atomicAdd(&A[LAB[(t << 2) + s]], 1);
    __syncthreads();
    // stable ascending argsort rank via key = count*NPTS + v; last 512 -> arange
    for (int s = 0; s < 4; ++s){
      int v = (t << 2) + s;
      int keyv = A[v] * NPTS + v;
      int pos = 0;
      for (int u = 0; u < NPTS; ++u) pos += ((A[u] * NPTS + u) < keyv) ? 1 : 0;
      Bb[v] = (pos >= NPTS - MAXSP) ? (pos - (NPTS - MAXSP)) : 0;
    }
    __syncthreads();
    for (int s = 0; s < 4; ++s){ int v = (t << 2) + s; LAB[v] = Bb[LAB[v]]; }
    __syncthreads();
  }
  int* og = out + (b << 12);
  for (int s = 0; s < 4; ++s){ int v = (t << 2) + s; og[v] = LAB[v]; }
}

// ---------------- launch ----------------------------------------------------
extern "C" void kernel_launch(void* const* d_in, const int* in_sizes, int n_in,
                              void* d_out, int out_size, void* d_ws, size_t ws_size,
                              hipStream_t stream){
  const float* coords = (const float*)d_in[0];
  int* out = (int*)d_out;
  int batches = in_sizes[0] / (NPTS * 3);   // 8

  char* ws = (char*)d_ws;
  unsigned long long* adj = (unsigned long long*)ws;                  // 16 MB
  size_t off = (size_t)batches * NPTS * NW * sizeof(unsigned long long);
  float4* pts = (float4*)(ws + off); off += (size_t)batches * NPTS * sizeof(float4);
  int* rcnt   = (int*)(ws + off); off += (size_t)batches * NPTS * sizeof(int);
  int* roff   = (int*)(ws + off); off += (size_t)batches * NPTS * sizeof(int);
  int* ecnt   = (int*)(ws + off); off += 256;
  uint32_t* edges = (uint32_t*)(ws + off); off += (size_t)batches * ECAP * sizeof(uint32_t);

  int npts_all = batches * NPTS;   // 32768
  // K0: pack float4(x,y,z,sq)
  k_prep<<<npts_all / 256, 256, 0, stream>>>(coords, pts);
  // K1: upper-triangle adjacency + per-row j>i counts
  k_adj<<<npts_all / (ROWS * 4), 256, 0, stream>>>(pts, adj, rcnt);
  // K2: per-batch scan -> deterministic edge offsets
  k_escan<<<batches, 1024, 0, stream>>>(rcnt, roff, ecnt);
  // K3: fill all j>i adjacent pairs
  k_efill<<<npts_all / 4, 256, 0, stream>>>(adj, roff, edges);
  // K4: per-batch mega kernel (incidence/core/UF/labels/border/finalize)
  k_mega<<<batches, 1024, 0, stream>>>(edges, ecnt, out);
}

// Round 11
// 66.746 us; speedup vs baseline: 4.7134x; 1.2808x over previous
//
#include <hip/hip_runtime.h>
#include <stdint.h>

#define NPTS 4096
#define SENT NPTS
#define MAXSP 512
#define ECAP 65536         // edge capacity per batch (pairs; ~8x margin)
#define ECACHE 16384       // edges cached in LDS by k_mega (64 KB)

typedef unsigned long long ull;

// ---------------- LDS union-find (union-by-min: root = component min) -------
__device__ __forceinline__ int find_lds(int* p, int x){
  while (true){
    int px = p[x];
    if (px == x) return x;
    int ppx = p[px];
    if (ppx == px) return px;
    p[x] = ppx;            // path halving (benign race; links only decrease)
    x = ppx;
  }
}

__device__ __forceinline__ void union_lds(int* p, int a, int b){
  a = find_lds(p, a);
  b = find_lds(p, b);
  while (a != b){
    int lo = min(a, b), hi = max(a, b);
    int old = atomicCAS(&p[hi], hi, lo);   // LDS CAS
    if (old == hi || old == lo) return;
    a = lo; b = old;                        // old = hi's true parent (< hi)
  }
}

// j>i diagonal mask for word at lane base
__device__ __forceinline__ ull trimask(ull m, int i, int base){
  if (base + 63 <= i) return 0ULL;
  if (base <= i) return m & ((~0ULL) << (i - base + 1));
  return m;
}

// ---------------- K0: pack coords into float4(x,y,z,sq); zero edge counters -
__global__ void k_prep(const float* __restrict__ coords,
                       float4* __restrict__ pts,
                       int* __restrict__ ecnt, int batches){
#pragma clang fp contract(off)
  int g = blockIdx.x * blockDim.x + threadIdx.x;
  if (blockIdx.x == 0 && threadIdx.x < batches) ecnt[threadIdx.x << 6] = 0;
  float x = coords[g*3+0], y = coords[g*3+1], z = coords[g*3+2];
  // sq: round each square, then sequential adds (XLA mul + reduce, no FMA)
  float sq = ((x*x) + (y*y)) + (z*z);
  pts[g] = make_float4(x, y, z, sq);
}

// ---------------- K1: balanced upper-triangle adjacency -> direct edge emit -
// d2 is bit-exactly symmetric, so only j>i is computed. Each wave takes 2 low
// rows (i0,i0+1) + 2 mirror high rows (4094-i0,4095-i0): uniform ~65 k-iters
// per wave -> no occupancy decay. Edges written straight from registers at
// block-atomic-allocated offsets (order nondeterministic, SET deterministic;
// every downstream consumer is order-independent).
__global__ void k_adj(const float4* __restrict__ pts,
                      uint32_t* __restrict__ edges,
                      int* __restrict__ ecnt){
#pragma clang fp contract(off)
  __shared__ int sTot, sBase;
  int tid  = threadIdx.x;
  int wv   = (blockIdx.x * blockDim.x + tid) >> 6;   // 8192 waves total
  int lane = tid & 63;
  int b = wv >> 10;                 // 1024 waves per batch
  int m = wv & 1023;
  int i0 = m << 1;                  // low rows i0, i0+1
  int h0 = (NPTS - 2) - i0;         // high rows h0, h0+1
  const float4* pb = pts + (b << 12);
  if (tid == 0) sTot = 0;
  __syncthreads();
  const float EPS2 = (float)(0.06 * 0.06);   // f64 product -> f32
  float4 p0 = pb[i0], p1 = pb[i0+1], p2 = pb[h0], p3 = pb[h0+1];
  ull w0 = 0, w1 = 0, w2 = 0, w3 = 0;
  int base = lane << 6;
  // group 0: rows i0, i0+1 (words W..63)
  {
    int W = i0 >> 6;
    float4 pj = pb[(W << 6) + lane];
    #pragma unroll 2
    for (int k = W; k < 64; ++k){
      float4 cur = pj;
      if (k + 1 < 64) pj = pb[((k + 1) << 6) + lane];   // prefetch next
      // dot: ascending-k FMA chain, first product plainly rounded (XLA gebp)
      float dotA = __builtin_fmaf(p0.z, cur.z, __builtin_fmaf(p0.y, cur.y, p0.x * cur.x));
      float d2A  = __builtin_fmaf(-2.0f, dotA, p0.w + cur.w);  // == rn(s-rn(2dot))
      float dotB = __builtin_fmaf(p1.z, cur.z, __builtin_fmaf(p1.y, cur.y, p1.x * cur.x));
      float d2B  = __builtin_fmaf(-2.0f, dotB, p1.w + cur.w);
      ull bA = __ballot(d2A <= EPS2);
      ull bB = __ballot(d2B <= EPS2);
      if (lane == k){ w0 = bA; w1 = bB; }
    }
  }
  // group 1: rows h0, h0+1 (words W..63)
  {
    int W = h0 >> 6;
    float4 pj = pb[(W << 6) + lane];
    #pragma unroll 2
    for (int k = W; k < 64; ++k){
      float4 cur = pj;
      if (k + 1 < 64) pj = pb[((k + 1) << 6) + lane];
      float dotA = __builtin_fmaf(p2.z, cur.z, __builtin_fmaf(p2.y, cur.y, p2.x * cur.x));
      float d2A  = __builtin_fmaf(-2.0f, dotA, p2.w + cur.w);
      float dotB = __builtin_fmaf(p3.z, cur.z, __builtin_fmaf(p3.y, cur.y, p3.x * cur.x));
      float d2B  = __builtin_fmaf(-2.0f, dotB, p3.w + cur.w);
      ull bA = __ballot(d2A <= EPS2);
      ull bB = __ballot(d2B <= EPS2);
      if (lane == k){ w2 = bA; w3 = bB; }
    }
  }
  // keep j > i only
  w0 = trimask(w0, i0,     base);
  w1 = trimask(w1, i0 + 1, base);
  w2 = trimask(w2, h0,     base);
  w3 = trimask(w3, h0 + 1, base);
  // per-lane edge count -> wave scan -> block LDS total -> one global atomic
  int cnt = __popcll(w0) + __popcll(w1) + __popcll(w2) + __popcll(w3);
  int incl = cnt;
  #pragma unroll
  for (int off = 1; off < 64; off <<= 1){
    int y = __shfl_up(incl, off);
    if (lane >= off) incl += y;
  }
  int total = __shfl(incl, 63);
  int woff = 0;
  if (lane == 63) woff = atomicAdd(&sTot, total);
  woff = __shfl(woff, 63);
  __syncthreads();                      // uniform work -> no divergence hazard
  if (tid == 0) sBase = atomicAdd(&ecnt[b << 6], sTot);  // padded 256B line
  __syncthreads();
  int pos = sBase + woff + incl - cnt;
  uint32_t* eb = edges + (size_t)b * ECAP;
  #define EMIT(mm, row) { ull e = (mm); while (e){ int bit = __builtin_ctzll(e); \
      e &= e - 1; if (pos < ECAP) eb[pos] = ((uint32_t)(row) << 12) | (uint32_t)(base + bit); ++pos; } }
  EMIT(w0, i0)
  EMIT(w1, i0 + 1)
  EMIT(w2, h0)
  EMIT(w3, h0 + 1)
  #undef EMIT
}

// ---------------- K2: per-batch mega kernel --------------------------------
// incidence -> core -> union-find -> labels -> border relax -> finalize,
// all in LDS; edges stream once from global, cached in LDS for reuse.
// deg[i] = 1 + incidence[i] (self-pair d2 ~ 2ulp << eps^2), so
// core <=> incidence >= 2 (MIN_SAMPLES=3).
__global__ __launch_bounds__(1024) void k_mega(const uint32_t* __restrict__ edges,
                                               const int* __restrict__ ecnt,
                                               int* __restrict__ out){
  __shared__ int par[NPTS];          // phase 1: incidence; then UF parent
  __shared__ int LAB[NPTS];
  __shared__ unsigned char corea[NPTS];
  __shared__ uint32_t ec[ECACHE];    // finalize aliases A/B/scan over this
  __shared__ int sMost;
  int b = blockIdx.x, t = threadIdx.x;
  int cnt = min(ecnt[b << 6], ECAP);
  const uint32_t* eb = edges + (size_t)b * ECAP;
  for (int s = 0; s < 4; ++s){ int v = (t << 2) + s; par[v] = 0; }
  if (t == 0) sMost = -1;
  __syncthreads();
  // P1: incidence counts + LDS edge cache
  for (int e = t; e < cnt; e += 1024){
    uint32_t pk = eb[e];
    if (e < ECACHE) ec[e] = pk;
    atomicAdd(&par[pk >> 12], 1);
    atomicAdd(&par[pk & 4095], 1);
  }
  __syncthreads();
  // P2: core flags, then reinit par as UF identity
  for (int s = 0; s < 4; ++s){ int v = (t << 2) + s; corea[v] = (par[v] >= 2) ? 1 : 0; }
  __syncthreads();
  for (int s = 0; s < 4; ++s){ int v = (t << 2) + s; par[v] = v; }
  __syncthreads();
  // P3: union core-core edges (single pass; fixed point = component min)
  for (int e = t; e < cnt; e += 1024){
    uint32_t pk = (e < ECACHE) ? ec[e] : eb[e];
    int u = pk >> 12, v = pk & 4095;
    if (corea[u] && corea[v]) union_lds(par, u, v);
  }
  __syncthreads();
  // P4: base labels (core: root; else SENT)
  for (int s = 0; s < 4; ++s){
    int v = (t << 2) + s;
    LAB[v] = corea[v] ? find_lds(par, v) : SENT;
  }
  __syncthreads();
  // P5: border relax — min core-neighbor root via the same edge list
  for (int e = t; e < cnt; e += 1024){
    uint32_t pk = (e < ECACHE) ? ec[e] : eb[e];
    int u = pk >> 12, v = pk & 4095;
    int cu = corea[u], cv = corea[v];
    if (cu && !cv)      atomicMin(&LAB[v], find_lds(par, u));
    else if (cv && !cu) atomicMin(&LAB[u], find_lds(par, v));
  }
  __syncthreads();
  // P6: finalize (noise fill, compact, cap) — A/B/scan aliased over ec
  int* A     = (int*)ec;
  int* Bb    = A + NPTS;
  int* scanb = Bb + NPTS;
  for (int s = 0; s < 4; ++s){ int v = (t << 2) + s; A[v] = 0; }
  __syncthreads();
  for (int s = 0; s < 4; ++s){ int l = LAB[(t << 2) + s]; if (l < SENT) atomicAdd(&A[l], 1); }
  __syncthreads();
  for (int s = 0; s < 4; ++s){
    int v = (t << 2) + s; int c = A[v];
    if (c > 0) atomicMax(&sMost, (c << 13) | (4095 - v));   // tie -> smallest label
  }
  __syncthreads();
  int most = (sMost >= 0) ? (4095 - (sMost & 8191)) : 0;
  for (int s = 0; s < 4; ++s){ int v = (t << 2) + s; if (LAB[v] == SENT) LAB[v] = most; Bb[v] = 0; }
  __syncthreads();
  for (int s = 0; s < 4; ++s) Bb[LAB[(t << 2) + s]] = 1;
  __syncthreads();
  int pv[4]; int ls = 0;
  for (int s = 0; s < 4; ++s){ pv[s] = Bb[(t << 2) + s]; ls += pv[s]; }
  scanb[t] = ls;
  __syncthreads();
  for (int off = 1; off < 1024; off <<= 1){
    int x = scanb[t];
    int y = (t >= off) ? scanb[t - off] : 0;
    __syncthreads();
    scanb[t] = x + y;
    __syncthreads();
  }
  int ncl = scanb[1023];
  int run = (t > 0) ? scanb[t - 1] : 0;
  for (int s = 0; s < 4; ++s){ run += pv[s]; Bb[(t << 2) + s] = run - 1; }
  __syncthreads();
  for (int s = 0; s < 4; ++s){ int v = (t << 2) + s; LAB[v] = Bb[LAB[v]]; }
  __syncthreads();
  if (ncl > MAXSP){
    // counts2 over compacted labels (0..ncl-1)
    for (int s = 0; s < 4; ++s) A[(t << 2) + s] = 0;
    __syncthreads();
    for (int s = 0; s < 4; ++s) atomicAdd(&A[LAB[(t << 2) + s]], 1);
    __syncthreads();
    // stable (count, index) rank over PRESENT labels only; absent labels
    // (count 0) occupy the first NPTS-ncl slots of the full argsort.
    for (int v = t; v < ncl; v += 1024){
      int keyv = A[v] * NPTS + v;
      int p = 0;
      for (int u = 0; u < ncl; ++u) p += ((A[u] * NPTS + u) < keyv) ? 1 : 0;
      int full = p + (NPTS - ncl);
      Bb[v] = (full >= NPTS - MAXSP) ? (full - (NPTS - MAXSP)) : 0;
    }
    __syncthreads();
    for (int s = 0; s < 4; ++s){ int v = (t << 2) + s; LAB[v] = Bb[LAB[v]]; }
    __syncthreads();
  }
  int* og = out + (b << 12);
  for (int s = 0; s < 4; ++s){ int v = (t << 2) + s; og[v] = LAB[v]; }
}

// ---------------- launch ----------------------------------------------------
extern "C" void kernel_launch(void* const* d_in, const int* in_sizes, int n_in,
                              void* d_out, int out_size, void* d_ws, size_t ws_size,
                              hipStream_t stream){
  const float* coords = (const float*)d_in[0];
  int* out = (int*)d_out;
  int batches = in_sizes[0] / (NPTS * 3);   // 8

  char* ws = (char*)d_ws;
  size_t off = 0;
  float4* pts = (float4*)(ws + off); off += (size_t)batches * NPTS * sizeof(float4);
  int* ecnt   = (int*)(ws + off);    off += (size_t)batches * 64 * sizeof(int); // 256B/batch
  uint32_t* edges = (uint32_t*)(ws + off); off += (size_t)batches * ECAP * sizeof(uint32_t);

  int npts_all = batches * NPTS;   // 32768
  // K0: pack float4(x,y,z,sq) + zero padded edge counters
  k_prep<<<npts_all / 256, 256, 0, stream>>>(coords, pts, ecnt, batches);
  // K1: balanced triangle adjacency -> direct edge emission
  //     waves = npts_all/4 (4 rows per wave); threads = waves*64; blocks = /256
  k_adj<<<npts_all / 16, 256, 0, stream>>>(pts, edges, ecnt);
  // K2: per-batch mega kernel (incidence/core/UF/labels/border/finalize)
  k_mega<<<batches, 1024, 0, stream>>>(edges, ecnt, out);
}

// Round 12
// 62.454 us; speedup vs baseline: 5.0373x; 1.0687x over previous
//
#include <hip/hip_runtime.h>
#include <stdint.h>

#define NPTS 4096
#define SENT NPTS
#define MAXSP 512
#define ECAP 65536         // edge capacity per batch (pairs; ~8x margin)
#define ECACHE 16384       // edges cached in LDS by k_mega (64 KB)

typedef unsigned long long ull;

// ---------------- LDS union-find (union-by-min: root = component min) -------
__device__ __forceinline__ int find_lds(int* p, int x){
  while (true){
    int px = p[x];
    if (px == x) return x;
    int ppx = p[px];
    if (ppx == px) return px;
    p[x] = ppx;            // path halving (benign race; links only decrease)
    x = ppx;
  }
}

__device__ __forceinline__ void union_lds(int* p, int a, int b){
  a = find_lds(p, a);
  b = find_lds(p, b);
  while (a != b){
    int lo = min(a, b), hi = max(a, b);
    int old = atomicCAS(&p[hi], hi, lo);   // LDS CAS
    if (old == hi || old == lo) return;
    a = lo; b = old;                        // old = hi's true parent (< hi)
  }
}

// j>i diagonal mask for word at lane base
__device__ __forceinline__ ull trimask(ull m, int i, int base){
  if (base + 63 <= i) return 0ULL;
  if (base <= i) return m & ((~0ULL) << (i - base + 1));
  return m;
}

// ---------------- K0: pack coords into float4(x,y,z,sq); zero edge counters -
__global__ void k_prep(const float* __restrict__ coords,
                       float4* __restrict__ pts,
                       int* __restrict__ ecnt, int batches){
#pragma clang fp contract(off)
  int g = blockIdx.x * blockDim.x + threadIdx.x;
  if (blockIdx.x == 0 && threadIdx.x < batches) ecnt[threadIdx.x << 6] = 0;
  float x = coords[g*3+0], y = coords[g*3+1], z = coords[g*3+2];
  // sq: round each square, then sequential adds (XLA mul + reduce, no FMA)
  float sq = ((x*x) + (y*y)) + (z*z);
  pts[g] = make_float4(x, y, z, sq);
}

// ---------------- K1: balanced upper-triangle adjacency -> direct edge emit -
// d2 is bit-exactly symmetric, so only j>i is computed. Each wave takes 4 low
// rows (i0..i0+3) + 4 mirror high rows (4092-i0..4095-i0): uniform ~65
// k-iters/wave AND 4 d2 per group-iter -> halved load traffic vs 2-row form.
// Edges written straight from registers at block-atomic-allocated offsets
// (order nondeterministic, SET deterministic; all consumers order-free).
__global__ void k_adj(const float4* __restrict__ pts,
                      uint32_t* __restrict__ edges,
                      int* __restrict__ ecnt){
#pragma clang fp contract(off)
  __shared__ int sTot, sBase;
  int tid  = threadIdx.x;
  int wv   = (blockIdx.x * blockDim.x + tid) >> 6;   // 4096 waves total
  int lane = tid & 63;
  int b = wv >> 9;                  // 512 waves per batch
  int m = wv & 511;
  int i0 = m << 2;                  // low rows i0..i0+3   (covers 0..2047)
  int h0 = (NPTS - 4) - i0;         // high rows h0..h0+3  (covers 2048..4095)
  const float4* pb = pts + (b << 12);
  if (tid == 0) sTot = 0;
  __syncthreads();
  const float EPS2 = (float)(0.06 * 0.06);   // f64 product -> f32
  float4 pL[4], pH[4];
  #pragma unroll
  for (int r = 0; r < 4; ++r){ pL[r] = pb[i0 + r]; pH[r] = pb[h0 + r]; }
  ull wl[4] = {0,0,0,0}, wh[4] = {0,0,0,0};
  int base = lane << 6;
  // group 0: low rows, words i0>>6 .. 63
  {
    int W = i0 >> 6;
    float4 pj = pb[(W << 6) + lane];
    for (int k = W; k < 64; ++k){
      float4 cur = pj;
      if (k + 1 < 64) pj = pb[((k + 1) << 6) + lane];   // prefetch next tile
      #pragma unroll
      for (int r = 0; r < 4; ++r){
        // dot: ascending-k FMA chain, first product plainly rounded (XLA gebp)
        float dot = __builtin_fmaf(pL[r].z, cur.z,
                    __builtin_fmaf(pL[r].y, cur.y, pL[r].x * cur.x));
        float d2  = __builtin_fmaf(-2.0f, dot, pL[r].w + cur.w); // ==rn(s-rn(2dot))
        ull bal = __ballot(d2 <= EPS2);
        if (lane == k) wl[r] = bal;
      }
    }
  }
  // group 1: high rows, words h0>>6 .. 63
  {
    int W = h0 >> 6;
    float4 pj = pb[(W << 6) + lane];
    for (int k = W; k < 64; ++k){
      float4 cur = pj;
      if (k + 1 < 64) pj = pb[((k + 1) << 6) + lane];
      #pragma unroll
      for (int r = 0; r < 4; ++r){
        float dot = __builtin_fmaf(pH[r].z, cur.z,
                    __builtin_fmaf(pH[r].y, cur.y, pH[r].x * cur.x));
        float d2  = __builtin_fmaf(-2.0f, dot, pH[r].w + cur.w);
        ull bal = __ballot(d2 <= EPS2);
        if (lane == k) wh[r] = bal;
      }
    }
  }
  // keep j > i only
  #pragma unroll
  for (int r = 0; r < 4; ++r){
    wl[r] = trimask(wl[r], i0 + r, base);
    wh[r] = trimask(wh[r], h0 + r, base);
  }
  // per-lane edge count -> wave scan -> block LDS total -> one global atomic
  int cnt = 0;
  #pragma unroll
  for (int r = 0; r < 4; ++r) cnt += __popcll(wl[r]) + __popcll(wh[r]);
  int incl = cnt;
  #pragma unroll
  for (int off = 1; off < 64; off <<= 1){
    int y = __shfl_up(incl, off);
    if (lane >= off) incl += y;
  }
  int total = __shfl(incl, 63);
  int woff = 0;
  if (lane == 63) woff = atomicAdd(&sTot, total);
  woff = __shfl(woff, 63);
  __syncthreads();                      // uniform work -> no divergence hazard
  if (tid == 0) sBase = atomicAdd(&ecnt[b << 6], sTot);  // padded 256B line
  __syncthreads();
  int pos = sBase + woff + incl - cnt;
  uint32_t* eb = edges + (size_t)b * ECAP;
  #define EMIT(mm, row) { ull e = (mm); while (e){ int bit = __builtin_ctzll(e); \
      e &= e - 1; if (pos < ECAP) eb[pos] = ((uint32_t)(row) << 12) | (uint32_t)(base + bit); ++pos; } }
  #pragma unroll
  for (int r = 0; r < 4; ++r) EMIT(wl[r], i0 + r)
  #pragma unroll
  for (int r = 0; r < 4; ++r) EMIT(wh[r], h0 + r)
  #undef EMIT
}

// ---------------- K2: per-batch mega kernel --------------------------------
// incidence -> core -> union-find -> labels -> border relax -> finalize,
// all in LDS; edges stream once from global, cached in LDS for reuse.
// deg[i] = 1 + incidence[i] (self-pair d2 ~ 2ulp << eps^2), so
// core <=> incidence >= 2 (MIN_SAMPLES=3).
__global__ __launch_bounds__(1024) void k_mega(const uint32_t* __restrict__ edges,
                                               const int* __restrict__ ecnt,
                                               int* __restrict__ out){
  __shared__ int par[NPTS];          // phase 1: incidence; then UF parent
  __shared__ int LAB[NPTS];
  __shared__ unsigned char corea[NPTS];
  __shared__ uint32_t ec[ECACHE];    // finalize aliases A/B over this
  __shared__ int wtots[16];
  __shared__ int sMost;
  int b = blockIdx.x, t = threadIdx.x;
  int wid = t >> 6, lane = t & 63;
  int cnt = min(ecnt[b << 6], ECAP);
  const uint32_t* eb = edges + (size_t)b * ECAP;
  for (int s = 0; s < 4; ++s){ int v = (t << 2) + s; par[v] = 0; }
  if (t == 0) sMost = -1;
  __syncthreads();
  // P1: incidence counts + LDS edge cache
  for (int e = t; e < cnt; e += 1024){
    uint32_t pk = eb[e];
    if (e < ECACHE) ec[e] = pk;
    atomicAdd(&par[pk >> 12], 1);
    atomicAdd(&par[pk & 4095], 1);
  }
  __syncthreads();
  // P2: core flags, then reinit par as UF identity
  for (int s = 0; s < 4; ++s){ int v = (t << 2) + s; corea[v] = (par[v] >= 2) ? 1 : 0; }
  __syncthreads();
  for (int s = 0; s < 4; ++s){ int v = (t << 2) + s; par[v] = v; }
  __syncthreads();
  // P3: union core-core edges (single pass; fixed point = component min)
  for (int e = t; e < cnt; e += 1024){
    uint32_t pk = (e < ECACHE) ? ec[e] : eb[e];
    int u = pk >> 12, v = pk & 4095;
    if (corea[u] && corea[v]) union_lds(par, u, v);
  }
  __syncthreads();
  // P4: base labels (core: root; else SENT)
  for (int s = 0; s < 4; ++s){
    int v = (t << 2) + s;
    LAB[v] = corea[v] ? find_lds(par, v) : SENT;
  }
  __syncthreads();
  // P5: border relax — min core-neighbor root via the same edge list
  for (int e = t; e < cnt; e += 1024){
    uint32_t pk = (e < ECACHE) ? ec[e] : eb[e];
    int u = pk >> 12, v = pk & 4095;
    int cu = corea[u], cv = corea[v];
    if (cu && !cv)      atomicMin(&LAB[v], find_lds(par, u));
    else if (cv && !cu) atomicMin(&LAB[u], find_lds(par, v));
  }
  __syncthreads();
  // P6: finalize (noise fill, compact, cap) — A/B aliased over ec
  int* A  = (int*)ec;
  int* Bb = A + NPTS;
  for (int s = 0; s < 4; ++s){ int v = (t << 2) + s; A[v] = 0; }
  __syncthreads();
  for (int s = 0; s < 4; ++s){ int l = LAB[(t << 2) + s]; if (l < SENT) atomicAdd(&A[l], 1); }
  __syncthreads();
  for (int s = 0; s < 4; ++s){
    int v = (t << 2) + s; int c = A[v];
    if (c > 0) atomicMax(&sMost, (c << 13) | (4095 - v));   // tie -> smallest label
  }
  __syncthreads();
  int most = (sMost >= 0) ? (4095 - (sMost & 8191)) : 0;
  for (int s = 0; s < 4; ++s){ int v = (t << 2) + s; if (LAB[v] == SENT) LAB[v] = most; Bb[v] = 0; }
  __syncthreads();
  for (int s = 0; s < 4; ++s) Bb[LAB[(t << 2) + s]] = 1;
  __syncthreads();
  // presence scan: wave shfl-scan + 16 wave totals -> rank = cumsum-1
  int pv[4]; int ls = 0;
  for (int s = 0; s < 4; ++s){ pv[s] = Bb[(t << 2) + s]; ls += pv[s]; }
  int incl = ls;
  #pragma unroll
  for (int off = 1; off < 64; off <<= 1){
    int y = __shfl_up(incl, off);
    if (lane >= off) incl += y;
  }
  if (lane == 63) wtots[wid] = incl;
  __syncthreads();
  int wbase = 0, ncl = 0;
  #pragma unroll
  for (int w = 0; w < 16; ++w){
    int wt = wtots[w];
    if (w < wid) wbase += wt;
    ncl += wt;
  }
  int run = wbase + incl - ls;
  for (int s = 0; s < 4; ++s){ run += pv[s]; Bb[(t << 2) + s] = run - 1; }
  __syncthreads();
  for (int s = 0; s < 4; ++s){ int v = (t << 2) + s; LAB[v] = Bb[LAB[v]]; }
  __syncthreads();
  if (ncl > MAXSP){
    // counts2 over compacted labels (0..ncl-1)
    for (int s = 0; s < 4; ++s) A[(t << 2) + s] = 0;
    __syncthreads();
    for (int s = 0; s < 4; ++s) atomicAdd(&A[LAB[(t << 2) + s]], 1);
    __syncthreads();
    // stable (count, index) rank over PRESENT labels only; absent labels
    // (count 0) occupy the first NPTS-ncl slots of the full argsort.
    for (int v = t; v < ncl; v += 1024){
      int keyv = A[v] * NPTS + v;
      int p = 0;
      for (int u = 0; u < ncl; ++u) p += ((A[u] * NPTS + u) < keyv) ? 1 : 0;
      int full = p + (NPTS - ncl);
      Bb[v] = (full >= NPTS - MAXSP) ? (full - (NPTS - MAXSP)) : 0;
    }
    __syncthreads();
    for (int s = 0; s < 4; ++s){ int v = (t << 2) + s; LAB[v] = Bb[LAB[v]]; }
    __syncthreads();
  }
  int* og = out + (b << 12);
  for (int s = 0; s < 4; ++s){ int v = (t << 2) + s; og[v] = LAB[v]; }
}

// ---------------- launch ----------------------------------------------------
extern "C" void kernel_launch(void* const* d_in, const int* in_sizes, int n_in,
                              void* d_out, int out_size, void* d_ws, size_t ws_size,
                              hipStream_t stream){
  const float* coords = (const float*)d_in[0];
  int* out = (int*)d_out;
  int batches = in_sizes[0] / (NPTS * 3);   // 8

  char* ws = (char*)d_ws;
  size_t off = 0;
  float4* pts = (float4*)(ws + off); off += (size_t)batches * NPTS * sizeof(float4);
  int* ecnt   = (int*)(ws + off);    off += (size_t)batches * 64 * sizeof(int); // 256B/batch
  uint32_t* edges = (uint32_t*)(ws + off); off += (size_t)batches * ECAP * sizeof(uint32_t);

  int npts_all = batches * NPTS;   // 32768
  // K0: pack float4(x,y,z,sq) + zero padded edge counters
  k_prep<<<npts_all / 256, 256, 0, stream>>>(coords, pts, ecnt, batches);
  // K1: balanced triangle adjacency -> direct edge emission
  //     waves = npts_all/8 = 4096 (8 rows per wave); threads = 4096*64;
  //     blocks = 4096*64/256 = npts_all/32 = 1024
  k_adj<<<npts_all / 32, 256, 0, stream>>>(pts, edges, ecnt);
  // K2: per-batch mega kernel (incidence/core/UF/labels/border/finalize)
  k_mega<<<batches, 1024, 0, stream>>>(edges, ecnt, out);
}